// Round 6
// baseline (276.172 us; speedup 1.0000x reference)
//
#include <hip/hip_runtime.h>
#include <math.h>

// ---------------- helpers ----------------
typedef short short8 __attribute__((ext_vector_type(8)));
typedef float floatx4 __attribute__((ext_vector_type(4)));

__device__ __forceinline__ float4 ld4(const float* p) { return *reinterpret_cast<const float4*>(p); }
__device__ __forceinline__ void st4(float* p, float4 v) { *reinterpret_cast<float4*>(p) = v; }

__device__ __forceinline__ float bf2f(unsigned int u) { return __uint_as_float(u << 16); }
__device__ __forceinline__ unsigned int f2bf1(float f) {
    unsigned int x = __float_as_uint(f);
    return (x + 0x7fffu + ((x >> 16) & 1u)) >> 16;  // RNE
}
__device__ __forceinline__ unsigned int f2bf2(float lo, float hi) {
    return f2bf1(lo) | (f2bf1(hi) << 16);
}
__device__ __forceinline__ void unpack8(uint4 v, float* f) {
    f[0] = bf2f(v.x & 0xffffu); f[1] = bf2f(v.x >> 16);
    f[2] = bf2f(v.y & 0xffffu); f[3] = bf2f(v.y >> 16);
    f[4] = bf2f(v.z & 0xffffu); f[5] = bf2f(v.z >> 16);
    f[6] = bf2f(v.w & 0xffffu); f[7] = bf2f(v.w >> 16);
}

// ---------------- CSR build ----------------
__global__ __launch_bounds__(256) void k_count(const int* __restrict__ dst, int* __restrict__ deg,
                                               int* __restrict__ rank, int E) {
    int e = blockIdx.x * 256 + threadIdx.x;
    if (e < E) rank[e] = atomicAdd(&deg[dst[e]], 1);
}

__global__ __launch_bounds__(256) void k_reduce256(const int* __restrict__ deg, int* __restrict__ bsum, int n) {
    __shared__ int s[256];
    int t = threadIdx.x;
    int i = blockIdx.x * 256 + t;
    s[t] = (i < n) ? deg[i] : 0;
    __syncthreads();
    for (int off = 128; off > 0; off >>= 1) {
        if (t < off) s[t] += s[t + off];
        __syncthreads();
    }
    if (t == 0) bsum[blockIdx.x] = s[0];
}

__global__ __launch_bounds__(256) void k_scan_small(const int* __restrict__ bsum, int* __restrict__ boff, int nb) {
    __shared__ int s[256];
    int t = threadIdx.x;
    int v = (t < nb) ? bsum[t] : 0;
    s[t] = v;
    __syncthreads();
    for (int off = 1; off < 256; off <<= 1) {
        int x = (t >= off) ? s[t - off] : 0;
        __syncthreads();
        s[t] += x;
        __syncthreads();
    }
    if (t < nb) boff[t] = s[t] - v;  // exclusive
}

__global__ __launch_bounds__(256) void k_scan_final(const int* __restrict__ deg, const int* __restrict__ boff,
                                                    int* __restrict__ row_off, float* __restrict__ dinv, int n) {
    __shared__ int s[256];
    int t = threadIdx.x;
    int i = blockIdx.x * 256 + t;
    int v = (i < n) ? deg[i] : 0;
    s[t] = v;
    __syncthreads();
    for (int off = 1; off < 256; off <<= 1) {
        int x = (t >= off) ? s[t - off] : 0;
        __syncthreads();
        s[t] += x;
        __syncthreads();
    }
    int incl = s[t] + boff[blockIdx.x];
    if (i < n) {
        row_off[i] = incl - v;
        dinv[i]    = 1.0f / sqrtf((float)v + 1.0f);
        if (i == n - 1) row_off[n] = incl;
    }
}

__global__ __launch_bounds__(256) void k_fill(const int* __restrict__ src, const int* __restrict__ dst,
                                              const int* __restrict__ rank, const int* __restrict__ roff,
                                              const float* __restrict__ dinv, int2* __restrict__ cpair, int E) {
    int e = blockIdx.x * 256 + threadIdx.x;
    if (e < E) {
        int s = src[e], d = dst[e];
        int pos = roff[d] + rank[e];
        cpair[pos] = make_int2(s, __float_as_int(dinv[s] * dinv[d]));
    }
}

// ---------------- all three W -> Wt (bf16, transposed) in one launch ----------------
__global__ __launch_bounds__(256) void k_prepW(const float* __restrict__ W1, const float* __restrict__ W2,
                                               const float* __restrict__ W3, unsigned short* __restrict__ Wt1,
                                               unsigned short* __restrict__ Wt2, unsigned short* __restrict__ Wt3) {
    int t = blockIdx.x * 256 + threadIdx.x;
    if (t < 16384) {
        int k = t & 127, n = t >> 7;
        Wt1[n * 128 + k] = (unsigned short)f2bf1(W1[(size_t)k * 128 + n]);
    } else if (t < 32768) {
        int u = t - 16384;
        int k = u & 127, n = u >> 7;
        Wt2[n * 128 + k] = (unsigned short)f2bf1(W2[(size_t)k * 128 + n]);
    } else if (t < 40960) {
        int u = t - 32768;
        int k = u & 127, n = u >> 7;
        Wt3[n * 128 + k] = (unsigned short)f2bf1(W3[(size_t)k * 64 + n]);
    }
}

// ---------------- layer-1 MFMA GEMM: O[nrows x 128](bf16) = X(f32)[nrows x 128] @ W ----------------
__global__ __launch_bounds__(256) void k_gemm1(const float* __restrict__ X, const unsigned short* __restrict__ Wt,
                                               unsigned short* __restrict__ O, int nrows) {
    constexpr int LDR = 136;
    __shared__ unsigned short sX[64 * LDR];
    __shared__ unsigned short sB[128 * LDR];

    const int tid  = threadIdx.x;
    const int row0 = blockIdx.x * 64;

#pragma unroll
    for (int i = 0; i < 4; ++i) {
        int idx = tid + i * 256;
        int r = idx >> 4, c8 = idx & 15;
        int grow = row0 + r;
        uint4 v = make_uint4(0, 0, 0, 0);
        if (grow < nrows) {
            float4 a = ld4(X + (size_t)grow * 128 + c8 * 8);
            float4 b = ld4(X + (size_t)grow * 128 + c8 * 8 + 4);
            v = make_uint4(f2bf2(a.x, a.y), f2bf2(a.z, a.w), f2bf2(b.x, b.y), f2bf2(b.z, b.w));
        }
        *reinterpret_cast<uint4*>(&sX[r * LDR + c8 * 8]) = v;
    }
#pragma unroll
    for (int i = 0; i < 8; ++i) {
        int idx = tid + i * 256;
        int n = idx >> 4, c8 = idx & 15;
        *reinterpret_cast<uint4*>(&sB[n * LDR + c8 * 8]) =
            *reinterpret_cast<const uint4*>(Wt + (size_t)n * 128 + c8 * 8);
    }
    __syncthreads();

    const int lane = tid & 63;
    const int wave = tid >> 6;
    const int l15  = lane & 15;
    const int quad = lane >> 4;

    floatx4 acc[8];
#pragma unroll
    for (int j = 0; j < 8; ++j) acc[j] = (floatx4){0.f, 0.f, 0.f, 0.f};

    const unsigned short* xbase = &sX[(wave * 16 + l15) * LDR + quad * 8];
#pragma unroll
    for (int kk = 0; kk < 4; ++kk) {
        short8 xb = *reinterpret_cast<const short8*>(xbase + kk * 32);
#pragma unroll
        for (int j = 0; j < 8; ++j) {
            short8 wa = *reinterpret_cast<const short8*>(&sB[(j * 16 + l15) * LDR + quad * 8 + kk * 32]);
            acc[j] = __builtin_amdgcn_mfma_f32_16x16x32_bf16(wa, xb, acc[j], 0, 0, 0);
        }
    }

    int xrow = row0 + wave * 16 + l15;
    if (xrow < nrows) {
#pragma unroll
        for (int j = 0; j < 8; ++j) {
            uint2 o = make_uint2(f2bf2(acc[j][0], acc[j][1]), f2bf2(acc[j][2], acc[j][3]));
            *reinterpret_cast<uint2*>(O + (size_t)xrow * 128 + j * 16 + quad * 4) = o;
        }
    }
}

// ---------------- fused: relu(agg(H)+bias) @ W -> O (bf16) ----------------
// agg phase: 16 lanes/node, 8 feats/lane, 8-deep gather pipeline, result -> LDS.
// mfma phase: same layout as k_gemm1 but W fragments read from global (L1/L2-hot),
// keeping LDS at 17.4KB so occupancy stays high for the latency-bound agg phase.
template <int NC>
__global__ __launch_bounds__(256) void k_agg_gemm(const unsigned short* __restrict__ H, const int* __restrict__ roff,
                                                  const int2* __restrict__ cpair, const float* __restrict__ dinv,
                                                  const float* __restrict__ bias, const unsigned short* __restrict__ Wt,
                                                  unsigned short* __restrict__ O, int n) {
    constexpr int LDR = 136;
    __shared__ unsigned short sX[64 * LDR];

    const int tid  = threadIdx.x;
    const int row0 = blockIdx.x * 64;
    const int g    = tid >> 4;        // node subgroup 0..15
    const int f8   = (tid & 15) * 8;  // feature offset

    float4 b0 = ld4(bias + f8);
    float4 b1 = ld4(bias + f8 + 4);
    float bb[8] = {b0.x, b0.y, b0.z, b0.w, b1.x, b1.y, b1.z, b1.w};

#pragma unroll
    for (int p = 0; p < 4; ++p) {
        int node = row0 + p * 16 + g;
        float a[8] = {0.f, 0.f, 0.f, 0.f, 0.f, 0.f, 0.f, 0.f};
        if (node < n) {
            float di = dinv[node];
            float sc = di * di;
            uint4 hv = *reinterpret_cast<const uint4*>(H + (size_t)node * 128 + f8);
            float h[8];
            unpack8(hv, h);
#pragma unroll
            for (int i = 0; i < 8; ++i) a[i] = h[i] * sc;

            int e  = roff[node];
            int e1 = roff[node + 1];
            for (; e + 7 < e1; e += 8) {
                int2 pr[8];
                uint4 v[8];
#pragma unroll
                for (int u = 0; u < 8; ++u) pr[u] = cpair[e + u];
#pragma unroll
                for (int u = 0; u < 8; ++u) v[u] = *reinterpret_cast<const uint4*>(H + (size_t)pr[u].x * 128 + f8);
#pragma unroll
                for (int u = 0; u < 8; ++u) {
                    float nu = __int_as_float(pr[u].y);
                    float gg[8];
                    unpack8(v[u], gg);
#pragma unroll
                    for (int i = 0; i < 8; ++i) a[i] += gg[i] * nu;
                }
            }
            if (e + 3 < e1) {
                int2 pr[4];
                uint4 v[4];
#pragma unroll
                for (int u = 0; u < 4; ++u) pr[u] = cpair[e + u];
#pragma unroll
                for (int u = 0; u < 4; ++u) v[u] = *reinterpret_cast<const uint4*>(H + (size_t)pr[u].x * 128 + f8);
#pragma unroll
                for (int u = 0; u < 4; ++u) {
                    float nu = __int_as_float(pr[u].y);
                    float gg[8];
                    unpack8(v[u], gg);
#pragma unroll
                    for (int i = 0; i < 8; ++i) a[i] += gg[i] * nu;
                }
                e += 4;
            }
            for (; e < e1; ++e) {
                int2 p0 = cpair[e];
                float n0 = __int_as_float(p0.y);
                uint4 v0 = *reinterpret_cast<const uint4*>(H + (size_t)p0.x * 128 + f8);
                float g0[8];
                unpack8(v0, g0);
#pragma unroll
                for (int i = 0; i < 8; ++i) a[i] += g0[i] * n0;
            }
#pragma unroll
            for (int i = 0; i < 8; ++i) a[i] = fmaxf(a[i] + bb[i], 0.0f);
        }
        uint4 ov = make_uint4(f2bf2(a[0], a[1]), f2bf2(a[2], a[3]), f2bf2(a[4], a[5]), f2bf2(a[6], a[7]));
        *reinterpret_cast<uint4*>(&sX[(p * 16 + g) * LDR + f8]) = ov;
    }
    __syncthreads();

    const int lane = tid & 63;
    const int wave = tid >> 6;
    const int l15  = lane & 15;
    const int quad = lane >> 4;

    floatx4 acc[NC / 16];
#pragma unroll
    for (int j = 0; j < NC / 16; ++j) acc[j] = (floatx4){0.f, 0.f, 0.f, 0.f};

    const unsigned short* xbase = &sX[(wave * 16 + l15) * LDR + quad * 8];
#pragma unroll
    for (int kk = 0; kk < 4; ++kk) {
        short8 xb = *reinterpret_cast<const short8*>(xbase + kk * 32);
#pragma unroll
        for (int j = 0; j < NC / 16; ++j) {
            short8 wa = *reinterpret_cast<const short8*>(Wt + (size_t)(j * 16 + l15) * 128 + quad * 8 + kk * 32);
            acc[j] = __builtin_amdgcn_mfma_f32_16x16x32_bf16(wa, xb, acc[j], 0, 0, 0);
        }
    }

    int xrow = row0 + wave * 16 + l15;
    if (xrow < n) {
#pragma unroll
        for (int j = 0; j < NC / 16; ++j) {
            uint2 o = make_uint2(f2bf2(acc[j][0], acc[j][1]), f2bf2(acc[j][2], acc[j][3]));
            *reinterpret_cast<uint2*>(O + (size_t)xrow * NC + j * 16 + quad * 4) = o;
        }
    }
}

// ---------------- aggregation (64 feats, bf16 H) + bias + log_softmax ----------------
// 8 lanes per node, 8 feats/lane, 8-deep gather pipeline.
__global__ __launch_bounds__(256) void k_agg_softmax(const unsigned short* __restrict__ H, const int* __restrict__ roff,
                                                     const int2* __restrict__ cpair, const float* __restrict__ dinv,
                                                     const float* __restrict__ bias, float* __restrict__ O, int n) {
    int t    = blockIdx.x * 256 + threadIdx.x;
    int node = t >> 3;
    int f8   = (t & 7) * 8;
    if (node >= n) return;

    float di = dinv[node];
    float sc = di * di;
    float a[8];
    {
        uint4 hv = *reinterpret_cast<const uint4*>(H + (size_t)node * 64 + f8);
        float h[8];
        unpack8(hv, h);
#pragma unroll
        for (int i = 0; i < 8; ++i) a[i] = h[i] * sc;
    }

    int e  = roff[node];
    int e1 = roff[node + 1];
    for (; e + 7 < e1; e += 8) {
        int2 pr[8];
        uint4 v[8];
#pragma unroll
        for (int u = 0; u < 8; ++u) pr[u] = cpair[e + u];
#pragma unroll
        for (int u = 0; u < 8; ++u) v[u] = *reinterpret_cast<const uint4*>(H + (size_t)pr[u].x * 64 + f8);
#pragma unroll
        for (int u = 0; u < 8; ++u) {
            float nu = __int_as_float(pr[u].y);
            float gg[8];
            unpack8(v[u], gg);
#pragma unroll
            for (int i = 0; i < 8; ++i) a[i] += gg[i] * nu;
        }
    }
    if (e + 3 < e1) {
        int2 pr[4];
        uint4 v[4];
#pragma unroll
        for (int u = 0; u < 4; ++u) pr[u] = cpair[e + u];
#pragma unroll
        for (int u = 0; u < 4; ++u) v[u] = *reinterpret_cast<const uint4*>(H + (size_t)pr[u].x * 64 + f8);
#pragma unroll
        for (int u = 0; u < 4; ++u) {
            float nu = __int_as_float(pr[u].y);
            float gg[8];
            unpack8(v[u], gg);
#pragma unroll
            for (int i = 0; i < 8; ++i) a[i] += gg[i] * nu;
        }
        e += 4;
    }
    for (; e < e1; ++e) {
        int2 p0 = cpair[e];
        float n0 = __int_as_float(p0.y);
        uint4 v0 = *reinterpret_cast<const uint4*>(H + (size_t)p0.x * 64 + f8);
        float g0[8];
        unpack8(v0, g0);
#pragma unroll
        for (int i = 0; i < 8; ++i) a[i] += g0[i] * n0;
    }

    float4 b0 = ld4(bias + f8);
    float4 b1 = ld4(bias + f8 + 4);
    float bb[8] = {b0.x, b0.y, b0.z, b0.w, b1.x, b1.y, b1.z, b1.w};
    float v[8];
#pragma unroll
    for (int i = 0; i < 8; ++i) v[i] = a[i] + bb[i];

    float m = v[0];
#pragma unroll
    for (int i = 1; i < 8; ++i) m = fmaxf(m, v[i]);
    m = fmaxf(m, __shfl_xor(m, 1));
    m = fmaxf(m, __shfl_xor(m, 2));
    m = fmaxf(m, __shfl_xor(m, 4));

    float ssum = 0.0f;
#pragma unroll
    for (int i = 0; i < 8; ++i) ssum += expf(v[i] - m);
    ssum += __shfl_xor(ssum, 1);
    ssum += __shfl_xor(ssum, 2);
    ssum += __shfl_xor(ssum, 4);
    float ls = logf(ssum);

    float* op = O + (size_t)node * 64 + f8;
    st4(op, make_float4(v[0] - m - ls, v[1] - m - ls, v[2] - m - ls, v[3] - m - ls));
    st4(op + 4, make_float4(v[4] - m - ls, v[5] - m - ls, v[6] - m - ls, v[7] - m - ls));
}

// ---------------- launch ----------------
extern "C" void kernel_launch(void* const* d_in, const int* in_sizes, int n_in,
                              void* d_out, int out_size, void* d_ws, size_t ws_size,
                              hipStream_t stream) {
    const float* x  = (const float*)d_in[0];
    const int*   ei = (const int*)d_in[1];
    const float* W1 = (const float*)d_in[2];
    const float* b1 = (const float*)d_in[3];
    const float* W2 = (const float*)d_in[4];
    const float* b2 = (const float*)d_in[5];
    const float* W3 = (const float*)d_in[6];
    const float* b3 = (const float*)d_in[7];
    float* out = (float*)d_out;

    const int N = in_sizes[0] / 128;
    const int E = in_sizes[1] / 2;
    const int* src = ei;
    const int* dst = ei + E;

    char* ws = (char*)d_ws;
    size_t off = 0;
    auto alloc = [&](size_t bytes) -> char* {
        char* p = ws + off;
        off = (off + bytes + 255) & ~(size_t)255;
        return p;
    };
    int nb = (N + 255) / 256;
    int*   deg     = (int*)alloc((size_t)N * 4);
    int*   row_off = (int*)alloc(((size_t)N + 1) * 4);
    float* dinv    = (float*)alloc((size_t)N * 4);
    int*   bsum    = (int*)alloc((size_t)nb * 4);
    int*   boff    = (int*)alloc((size_t)nb * 4);
    int*   rank    = (int*)alloc((size_t)E * 4);
    int2*  cpair   = (int2*)alloc((size_t)E * 8);
    unsigned short* Wt1  = (unsigned short*)alloc(128 * 128 * 2);
    unsigned short* Wt2  = (unsigned short*)alloc(128 * 128 * 2);
    unsigned short* Wt3  = (unsigned short*)alloc(64 * 128 * 2);
    unsigned short* bufA = (unsigned short*)alloc((size_t)N * 128 * 2);  // t1 = x@W1
    unsigned short* bufB = (unsigned short*)alloc((size_t)N * 128 * 2);  // t2
    unsigned short* bufC = (unsigned short*)alloc((size_t)N * 64 * 2);   // t3
    (void)ws_size; (void)n_in; (void)out_size;

    hipMemsetAsync(deg, 0, (size_t)N * 4, stream);
    k_count<<<(E + 255) / 256, 256, 0, stream>>>(dst, deg, rank, E);
    k_reduce256<<<nb, 256, 0, stream>>>(deg, bsum, N);
    k_scan_small<<<1, 256, 0, stream>>>(bsum, boff, nb);
    k_scan_final<<<nb, 256, 0, stream>>>(deg, boff, row_off, dinv, N);
    k_fill<<<(E + 255) / 256, 256, 0, stream>>>(src, dst, rank, row_off, dinv, cpair, E);

    k_prepW<<<(40960 + 255) / 256, 256, 0, stream>>>(W1, W2, W3, Wt1, Wt2, Wt3);

    int blocks64 = (N + 63) / 64;
    // t1 = x @ W1
    k_gemm1<<<blocks64, 256, 0, stream>>>(x, Wt1, bufA, N);
    // t2 = relu(agg(t1)+b1) @ W2
    k_agg_gemm<128><<<blocks64, 256, 0, stream>>>(bufA, row_off, cpair, dinv, b1, Wt2, bufB, N);
    // t3 = relu(agg(t2)+b2) @ W3
    k_agg_gemm<64><<<blocks64, 256, 0, stream>>>(bufB, row_off, cpair, dinv, b2, Wt3, bufC, N);
    // out = log_softmax(agg(t3)+b3)
    k_agg_softmax<<<((size_t)N * 8 + 255) / 256, 256, 0, stream>>>(bufC, row_off, cpair, dinv, b3, out, N);
}

// Round 7
// 269.186 us; speedup vs baseline: 1.0260x; 1.0260x over previous
//
#include <hip/hip_runtime.h>
#include <math.h>

// ---------------- helpers ----------------
typedef short short8 __attribute__((ext_vector_type(8)));
typedef float floatx4 __attribute__((ext_vector_type(4)));

__device__ __forceinline__ float4 ld4(const float* p) { return *reinterpret_cast<const float4*>(p); }
__device__ __forceinline__ void st4(float* p, float4 v) { *reinterpret_cast<float4*>(p) = v; }

__device__ __forceinline__ float bf2f(unsigned int u) { return __uint_as_float(u << 16); }
__device__ __forceinline__ unsigned int f2bf1(float f) {
    unsigned int x = __float_as_uint(f);
    return (x + 0x7fffu + ((x >> 16) & 1u)) >> 16;  // RNE
}
__device__ __forceinline__ unsigned int f2bf2(float lo, float hi) {
    return f2bf1(lo) | (f2bf1(hi) << 16);
}
__device__ __forceinline__ void unpack8(uint4 v, float* f) {
    f[0] = bf2f(v.x & 0xffffu); f[1] = bf2f(v.x >> 16);
    f[2] = bf2f(v.y & 0xffffu); f[3] = bf2f(v.y >> 16);
    f[4] = bf2f(v.z & 0xffffu); f[5] = bf2f(v.z >> 16);
    f[6] = bf2f(v.w & 0xffffu); f[7] = bf2f(v.w >> 16);
}

// ---------------- CSR build ----------------
__global__ __launch_bounds__(256) void k_count(const int* __restrict__ dst, int* __restrict__ deg,
                                               int* __restrict__ rank, int E) {
    int e = blockIdx.x * 256 + threadIdx.x;
    if (e < E) rank[e] = atomicAdd(&deg[dst[e]], 1);
}

__global__ __launch_bounds__(256) void k_reduce256(const int* __restrict__ deg, int* __restrict__ bsum, int n) {
    __shared__ int s[256];
    int t = threadIdx.x;
    int i = blockIdx.x * 256 + t;
    s[t] = (i < n) ? deg[i] : 0;
    __syncthreads();
    for (int off = 128; off > 0; off >>= 1) {
        if (t < off) s[t] += s[t + off];
        __syncthreads();
    }
    if (t == 0) bsum[blockIdx.x] = s[0];
}

__global__ __launch_bounds__(256) void k_scan_small(const int* __restrict__ bsum, int* __restrict__ boff, int nb) {
    __shared__ int s[256];
    int t = threadIdx.x;
    int v = (t < nb) ? bsum[t] : 0;
    s[t] = v;
    __syncthreads();
    for (int off = 1; off < 256; off <<= 1) {
        int x = (t >= off) ? s[t - off] : 0;
        __syncthreads();
        s[t] += x;
        __syncthreads();
    }
    if (t < nb) boff[t] = s[t] - v;  // exclusive
}

__global__ __launch_bounds__(256) void k_scan_final(const int* __restrict__ deg, const int* __restrict__ boff,
                                                    int* __restrict__ row_off, float* __restrict__ dinv, int n) {
    __shared__ int s[256];
    int t = threadIdx.x;
    int i = blockIdx.x * 256 + t;
    int v = (i < n) ? deg[i] : 0;
    s[t] = v;
    __syncthreads();
    for (int off = 1; off < 256; off <<= 1) {
        int x = (t >= off) ? s[t - off] : 0;
        __syncthreads();
        s[t] += x;
        __syncthreads();
    }
    int incl = s[t] + boff[blockIdx.x];
    if (i < n) {
        row_off[i] = incl - v;
        dinv[i]    = 1.0f / sqrtf((float)v + 1.0f);
        if (i == n - 1) row_off[n] = incl;
    }
}

__global__ __launch_bounds__(256) void k_fill(const int* __restrict__ src, const int* __restrict__ dst,
                                              const int* __restrict__ rank, const int* __restrict__ roff,
                                              const float* __restrict__ dinv, int2* __restrict__ cpair, int E) {
    int e = blockIdx.x * 256 + threadIdx.x;
    if (e < E) {
        int s = src[e], d = dst[e];
        int pos = roff[d] + rank[e];
        cpair[pos] = make_int2(s, __float_as_int(dinv[s] * dinv[d]));
    }
}

// ---------------- all three W -> Wt (bf16, transposed) in one launch ----------------
__global__ __launch_bounds__(256) void k_prepW(const float* __restrict__ W1, const float* __restrict__ W2,
                                               const float* __restrict__ W3, unsigned short* __restrict__ Wt1,
                                               unsigned short* __restrict__ Wt2, unsigned short* __restrict__ Wt3) {
    int t = blockIdx.x * 256 + threadIdx.x;
    if (t < 16384) {
        int k = t & 127, n = t >> 7;
        Wt1[n * 128 + k] = (unsigned short)f2bf1(W1[(size_t)k * 128 + n]);
    } else if (t < 32768) {
        int u = t - 16384;
        int k = u & 127, n = u >> 7;
        Wt2[n * 128 + k] = (unsigned short)f2bf1(W2[(size_t)k * 128 + n]);
    } else if (t < 40960) {
        int u = t - 32768;
        int k = u & 127, n = u >> 7;
        Wt3[n * 128 + k] = (unsigned short)f2bf1(W3[(size_t)k * 64 + n]);
    }
}

// ---------------- MFMA GEMM: O[nrows x NC](bf16) = X[nrows x 128] @ W[128 x NC] ----------------
// block = 256 threads (4 waves), 64 rows/block. LDS rows padded to 136 shorts.
// A=Wt-frag (m=w-col), B=X-frag (n=x-row) => D[row=quad*4+reg=w-col][col=lane&15=x-row].
template <int NC, bool XF32>
__global__ __launch_bounds__(256) void k_gemm_mfma(const void* __restrict__ Xv, const unsigned short* __restrict__ Wt,
                                                   unsigned short* __restrict__ O, int nrows) {
    constexpr int LDR = 136;
    __shared__ unsigned short sX[64 * LDR];
    __shared__ unsigned short sB[NC * LDR];

    const int tid  = threadIdx.x;
    const int row0 = blockIdx.x * 64;

    if constexpr (XF32) {
        const float* X = (const float*)Xv;
#pragma unroll
        for (int i = 0; i < 4; ++i) {
            int idx = tid + i * 256;
            int r = idx >> 4, c8 = idx & 15;
            int grow = row0 + r;
            uint4 v = make_uint4(0, 0, 0, 0);
            if (grow < nrows) {
                float4 a = ld4(X + (size_t)grow * 128 + c8 * 8);
                float4 b = ld4(X + (size_t)grow * 128 + c8 * 8 + 4);
                v = make_uint4(f2bf2(a.x, a.y), f2bf2(a.z, a.w), f2bf2(b.x, b.y), f2bf2(b.z, b.w));
            }
            *reinterpret_cast<uint4*>(&sX[r * LDR + c8 * 8]) = v;
        }
    } else {
        const unsigned short* X = (const unsigned short*)Xv;
#pragma unroll
        for (int i = 0; i < 4; ++i) {
            int idx = tid + i * 256;
            int r = idx >> 4, c8 = idx & 15;
            int grow = row0 + r;
            uint4 v = make_uint4(0, 0, 0, 0);
            if (grow < nrows) v = *reinterpret_cast<const uint4*>(X + (size_t)grow * 128 + c8 * 8);
            *reinterpret_cast<uint4*>(&sX[r * LDR + c8 * 8]) = v;
        }
    }
#pragma unroll
    for (int i = 0; i < NC / 16; ++i) {
        int idx = tid + i * 256;
        int n = idx >> 4, c8 = idx & 15;
        *reinterpret_cast<uint4*>(&sB[n * LDR + c8 * 8]) =
            *reinterpret_cast<const uint4*>(Wt + (size_t)n * 128 + c8 * 8);
    }
    __syncthreads();

    const int lane = tid & 63;
    const int wave = tid >> 6;
    const int l15  = lane & 15;
    const int quad = lane >> 4;

    floatx4 acc[NC / 16];
#pragma unroll
    for (int j = 0; j < NC / 16; ++j) acc[j] = (floatx4){0.f, 0.f, 0.f, 0.f};

    const unsigned short* xbase = &sX[(wave * 16 + l15) * LDR + quad * 8];
#pragma unroll
    for (int kk = 0; kk < 4; ++kk) {
        short8 xb = *reinterpret_cast<const short8*>(xbase + kk * 32);
#pragma unroll
        for (int j = 0; j < NC / 16; ++j) {
            short8 wa = *reinterpret_cast<const short8*>(&sB[(j * 16 + l15) * LDR + quad * 8 + kk * 32]);
            acc[j] = __builtin_amdgcn_mfma_f32_16x16x32_bf16(wa, xb, acc[j], 0, 0, 0);
        }
    }

    int xrow = row0 + wave * 16 + l15;
    if (xrow < nrows) {
#pragma unroll
        for (int j = 0; j < NC / 16; ++j) {
            uint2 o = make_uint2(f2bf2(acc[j][0], acc[j][1]), f2bf2(acc[j][2], acc[j][3]));
            *reinterpret_cast<uint2*>(O + (size_t)xrow * NC + j * 16 + quad * 4) = o;
        }
    }
}

// ---------------- aggregation (128 feats, bf16 H) + bias + relu ----------------
// 16 lanes/node, 8 feats (16 B)/lane; 8-deep gather pipeline for MLP.
__global__ __launch_bounds__(256) void k_agg_relu(const unsigned short* __restrict__ H, const int* __restrict__ roff,
                                                  const int2* __restrict__ cpair, const float* __restrict__ dinv,
                                                  const float* __restrict__ bias, unsigned short* __restrict__ O, int n) {
    int t    = blockIdx.x * 256 + threadIdx.x;
    int node = t >> 4;
    int f8   = (t & 15) * 8;
    if (node >= n) return;

    float di = dinv[node];
    float sc = di * di;
    float a[8];
    {
        uint4 hv = *reinterpret_cast<const uint4*>(H + (size_t)node * 128 + f8);
        float h[8];
        unpack8(hv, h);
#pragma unroll
        for (int i = 0; i < 8; ++i) a[i] = h[i] * sc;
    }

    int e  = roff[node];
    int e1 = roff[node + 1];
    for (; e + 7 < e1; e += 8) {
        int2 pr[8];
        uint4 v[8];
#pragma unroll
        for (int u = 0; u < 8; ++u) pr[u] = cpair[e + u];
#pragma unroll
        for (int u = 0; u < 8; ++u) v[u] = *reinterpret_cast<const uint4*>(H + (size_t)pr[u].x * 128 + f8);
#pragma unroll
        for (int u = 0; u < 8; ++u) {
            float nu = __int_as_float(pr[u].y);
            float gg[8];
            unpack8(v[u], gg);
#pragma unroll
            for (int i = 0; i < 8; ++i) a[i] += gg[i] * nu;
        }
    }
    if (e + 3 < e1) {
        int2 pr[4];
        uint4 v[4];
#pragma unroll
        for (int u = 0; u < 4; ++u) pr[u] = cpair[e + u];
#pragma unroll
        for (int u = 0; u < 4; ++u) v[u] = *reinterpret_cast<const uint4*>(H + (size_t)pr[u].x * 128 + f8);
#pragma unroll
        for (int u = 0; u < 4; ++u) {
            float nu = __int_as_float(pr[u].y);
            float gg[8];
            unpack8(v[u], gg);
#pragma unroll
            for (int i = 0; i < 8; ++i) a[i] += gg[i] * nu;
        }
        e += 4;
    }
    for (; e < e1; ++e) {
        int2 p0 = cpair[e];
        float n0 = __int_as_float(p0.y);
        uint4 v0 = *reinterpret_cast<const uint4*>(H + (size_t)p0.x * 128 + f8);
        float g0[8];
        unpack8(v0, g0);
#pragma unroll
        for (int i = 0; i < 8; ++i) a[i] += g0[i] * n0;
    }

    float4 b0 = ld4(bias + f8);
    float4 b1 = ld4(bias + f8 + 4);
    float bb[8] = {b0.x, b0.y, b0.z, b0.w, b1.x, b1.y, b1.z, b1.w};
#pragma unroll
    for (int i = 0; i < 8; ++i) a[i] = fmaxf(a[i] + bb[i], 0.0f);

    uint4 ov = make_uint4(f2bf2(a[0], a[1]), f2bf2(a[2], a[3]), f2bf2(a[4], a[5]), f2bf2(a[6], a[7]));
    *reinterpret_cast<uint4*>(O + (size_t)node * 128 + f8) = ov;
}

// ---------------- aggregation (64 feats, bf16 H) + bias + log_softmax ----------------
// 8 lanes/node, 8 feats/lane, 8-deep gather pipeline.
__global__ __launch_bounds__(256) void k_agg_softmax(const unsigned short* __restrict__ H, const int* __restrict__ roff,
                                                     const int2* __restrict__ cpair, const float* __restrict__ dinv,
                                                     const float* __restrict__ bias, float* __restrict__ O, int n) {
    int t    = blockIdx.x * 256 + threadIdx.x;
    int node = t >> 3;
    int f8   = (t & 7) * 8;
    if (node >= n) return;

    float di = dinv[node];
    float sc = di * di;
    float a[8];
    {
        uint4 hv = *reinterpret_cast<const uint4*>(H + (size_t)node * 64 + f8);
        float h[8];
        unpack8(hv, h);
#pragma unroll
        for (int i = 0; i < 8; ++i) a[i] = h[i] * sc;
    }

    int e  = roff[node];
    int e1 = roff[node + 1];
    for (; e + 7 < e1; e += 8) {
        int2 pr[8];
        uint4 v[8];
#pragma unroll
        for (int u = 0; u < 8; ++u) pr[u] = cpair[e + u];
#pragma unroll
        for (int u = 0; u < 8; ++u) v[u] = *reinterpret_cast<const uint4*>(H + (size_t)pr[u].x * 64 + f8);
#pragma unroll
        for (int u = 0; u < 8; ++u) {
            float nu = __int_as_float(pr[u].y);
            float gg[8];
            unpack8(v[u], gg);
#pragma unroll
            for (int i = 0; i < 8; ++i) a[i] += gg[i] * nu;
        }
    }
    if (e + 3 < e1) {
        int2 pr[4];
        uint4 v[4];
#pragma unroll
        for (int u = 0; u < 4; ++u) pr[u] = cpair[e + u];
#pragma unroll
        for (int u = 0; u < 4; ++u) v[u] = *reinterpret_cast<const uint4*>(H + (size_t)pr[u].x * 64 + f8);
#pragma unroll
        for (int u = 0; u < 4; ++u) {
            float nu = __int_as_float(pr[u].y);
            float gg[8];
            unpack8(v[u], gg);
#pragma unroll
            for (int i = 0; i < 8; ++i) a[i] += gg[i] * nu;
        }
        e += 4;
    }
    for (; e < e1; ++e) {
        int2 p0 = cpair[e];
        float n0 = __int_as_float(p0.y);
        uint4 v0 = *reinterpret_cast<const uint4*>(H + (size_t)p0.x * 64 + f8);
        float g0[8];
        unpack8(v0, g0);
#pragma unroll
        for (int i = 0; i < 8; ++i) a[i] += g0[i] * n0;
    }

    float4 b0 = ld4(bias + f8);
    float4 b1 = ld4(bias + f8 + 4);
    float bb[8] = {b0.x, b0.y, b0.z, b0.w, b1.x, b1.y, b1.z, b1.w};
    float v[8];
#pragma unroll
    for (int i = 0; i < 8; ++i) v[i] = a[i] + bb[i];

    float m = v[0];
#pragma unroll
    for (int i = 1; i < 8; ++i) m = fmaxf(m, v[i]);
    m = fmaxf(m, __shfl_xor(m, 1));
    m = fmaxf(m, __shfl_xor(m, 2));
    m = fmaxf(m, __shfl_xor(m, 4));

    float ssum = 0.0f;
#pragma unroll
    for (int i = 0; i < 8; ++i) ssum += expf(v[i] - m);
    ssum += __shfl_xor(ssum, 1);
    ssum += __shfl_xor(ssum, 2);
    ssum += __shfl_xor(ssum, 4);
    float ls = logf(ssum);

    float* op = O + (size_t)node * 64 + f8;
    st4(op, make_float4(v[0] - m - ls, v[1] - m - ls, v[2] - m - ls, v[3] - m - ls));
    st4(op + 4, make_float4(v[4] - m - ls, v[5] - m - ls, v[6] - m - ls, v[7] - m - ls));
}

// ---------------- launch ----------------
extern "C" void kernel_launch(void* const* d_in, const int* in_sizes, int n_in,
                              void* d_out, int out_size, void* d_ws, size_t ws_size,
                              hipStream_t stream) {
    const float* x  = (const float*)d_in[0];
    const int*   ei = (const int*)d_in[1];
    const float* W1 = (const float*)d_in[2];
    const float* b1 = (const float*)d_in[3];
    const float* W2 = (const float*)d_in[4];
    const float* b2 = (const float*)d_in[5];
    const float* W3 = (const float*)d_in[6];
    const float* b3 = (const float*)d_in[7];
    float* out = (float*)d_out;

    const int N = in_sizes[0] / 128;
    const int E = in_sizes[1] / 2;
    const int* src = ei;
    const int* dst = ei + E;

    char* ws = (char*)d_ws;
    size_t off = 0;
    auto alloc = [&](size_t bytes) -> char* {
        char* p = ws + off;
        off = (off + bytes + 255) & ~(size_t)255;
        return p;
    };
    int nb = (N + 255) / 256;
    int*   deg     = (int*)alloc((size_t)N * 4);
    int*   row_off = (int*)alloc(((size_t)N + 1) * 4);
    float* dinv    = (float*)alloc((size_t)N * 4);
    int*   bsum    = (int*)alloc((size_t)nb * 4);
    int*   boff    = (int*)alloc((size_t)nb * 4);
    int*   rank    = (int*)alloc((size_t)E * 4);
    int2*  cpair   = (int2*)alloc((size_t)E * 8);
    unsigned short* Wt1  = (unsigned short*)alloc(128 * 128 * 2);
    unsigned short* Wt2  = (unsigned short*)alloc(128 * 128 * 2);
    unsigned short* Wt3  = (unsigned short*)alloc(64 * 128 * 2);
    unsigned short* bufA = (unsigned short*)alloc((size_t)N * 128 * 2);
    unsigned short* bufB = (unsigned short*)alloc((size_t)N * 128 * 2);
    unsigned short* bufC = (unsigned short*)alloc((size_t)N * 64 * 2);
    (void)ws_size; (void)n_in; (void)out_size;

    hipMemsetAsync(deg, 0, (size_t)N * 4, stream);
    k_count<<<(E + 255) / 256, 256, 0, stream>>>(dst, deg, rank, E);
    k_reduce256<<<nb, 256, 0, stream>>>(deg, bsum, N);
    k_scan_small<<<1, 256, 0, stream>>>(bsum, boff, nb);
    k_scan_final<<<nb, 256, 0, stream>>>(deg, boff, row_off, dinv, N);
    k_fill<<<(E + 255) / 256, 256, 0, stream>>>(src, dst, rank, row_off, dinv, cpair, E);

    k_prepW<<<(40960 + 255) / 256, 256, 0, stream>>>(W1, W2, W3, Wt1, Wt2, Wt3);

    int blocks64 = (N + 63) / 64;
    // layer 1 (f32 x converted during staging)
    k_gemm_mfma<128, true><<<blocks64, 256, 0, stream>>>(x, Wt1, bufA, N);
    k_agg_relu<<<((size_t)N * 16 + 255) / 256, 256, 0, stream>>>(bufA, row_off, cpair, dinv, b1, bufB, N);
    // layer 2
    k_gemm_mfma<128, false><<<blocks64, 256, 0, stream>>>(bufB, Wt2, bufA, N);
    k_agg_relu<<<((size_t)N * 16 + 255) / 256, 256, 0, stream>>>(bufA, row_off, cpair, dinv, b2, bufB, N);
    // layer 3 + log_softmax
    k_gemm_mfma<64, false><<<blocks64, 256, 0, stream>>>(bufB, Wt3, bufC, N);
    k_agg_softmax<<<((size_t)N * 8 + 255) / 256, 256, 0, stream>>>(bufC, row_off, cpair, dinv, b3, out, N);
}

// Round 8
// 256.297 us; speedup vs baseline: 1.0775x; 1.0503x over previous
//
#include <hip/hip_runtime.h>
#include <math.h>

// ---------------- helpers ----------------
typedef short short8 __attribute__((ext_vector_type(8)));
typedef float floatx4 __attribute__((ext_vector_type(4)));

__device__ __forceinline__ float4 ld4(const float* p) { return *reinterpret_cast<const float4*>(p); }
__device__ __forceinline__ void st4(float* p, float4 v) { *reinterpret_cast<float4*>(p) = v; }

__device__ __forceinline__ float bf2f(unsigned int u) { return __uint_as_float(u << 16); }
__device__ __forceinline__ unsigned int f2bf1(float f) {
    unsigned int x = __float_as_uint(f);
    return (x + 0x7fffu + ((x >> 16) & 1u)) >> 16;  // RNE
}
__device__ __forceinline__ unsigned int f2bf2(float lo, float hi) {
    return f2bf1(lo) | (f2bf1(hi) << 16);
}
__device__ __forceinline__ void unpack8(uint4 v, float* f) {
    f[0] = bf2f(v.x & 0xffffu); f[1] = bf2f(v.x >> 16);
    f[2] = bf2f(v.y & 0xffffu); f[3] = bf2f(v.y >> 16);
    f[4] = bf2f(v.z & 0xffffu); f[5] = bf2f(v.z >> 16);
    f[6] = bf2f(v.w & 0xffffu); f[7] = bf2f(v.w >> 16);
}

// ---------------- launch A: edge count/rank + all-W transpose (independent work merged) ----------------
// blocks [0, nbE): count; blocks [nbE, nbE+160): prepW.
__global__ __launch_bounds__(256) void k_count_prep(const int* __restrict__ dst, int* __restrict__ deg,
                                                    int* __restrict__ rank, int E, int nbE,
                                                    const float* __restrict__ W1, const float* __restrict__ W2,
                                                    const float* __restrict__ W3, unsigned short* __restrict__ Wt1,
                                                    unsigned short* __restrict__ Wt2, unsigned short* __restrict__ Wt3) {
    if ((int)blockIdx.x < nbE) {
        int e = blockIdx.x * 256 + threadIdx.x;
        if (e < E) rank[e] = atomicAdd(&deg[dst[e]], 1);
    } else {
        int t = (blockIdx.x - nbE) * 256 + threadIdx.x;
        if (t < 16384) {
            int k = t & 127, n = t >> 7;
            Wt1[n * 128 + k] = (unsigned short)f2bf1(W1[(size_t)k * 128 + n]);
        } else if (t < 32768) {
            int u = t - 16384;
            int k = u & 127, n = u >> 7;
            Wt2[n * 128 + k] = (unsigned short)f2bf1(W2[(size_t)k * 128 + n]);
        } else if (t < 40960) {
            int u = t - 32768;
            int k = u & 127, n = u >> 7;
            Wt3[n * 128 + k] = (unsigned short)f2bf1(W3[(size_t)k * 64 + n]);
        }
    }
}

// ---------------- launch B: deg block-reduce + layer-1 MFMA GEMM (independent work merged) ----------------
// blocks [0, nb): reduce256 over deg; blocks [nb, nb+blocks64): gemm1 (x f32 -> bf16 staging).
// Shared-memory arena aliased per branch (branch-exclusive usage).
__global__ __launch_bounds__(256) void k_reduce_gemm1(const int* __restrict__ deg, int* __restrict__ bsum, int n, int nb,
                                                      const float* __restrict__ X, const unsigned short* __restrict__ Wt,
                                                      unsigned short* __restrict__ O, int nrows) {
    constexpr int LDR = 136;
    __shared__ __align__(16) unsigned char smem[(64 * LDR + 128 * LDR) * 2];  // 52224 B

    const int tid = threadIdx.x;
    if ((int)blockIdx.x < nb) {
        int* s = (int*)smem;
        int i = blockIdx.x * 256 + tid;
        s[tid] = (i < n) ? deg[i] : 0;
        __syncthreads();
        for (int off = 128; off > 0; off >>= 1) {
            if (tid < off) s[tid] += s[tid + off];
            __syncthreads();
        }
        if (tid == 0) bsum[blockIdx.x] = s[0];
        return;
    }

    unsigned short* sX = (unsigned short*)smem;
    unsigned short* sB = sX + 64 * LDR;
    const int row0 = (blockIdx.x - nb) * 64;

#pragma unroll
    for (int i = 0; i < 4; ++i) {
        int idx = tid + i * 256;
        int r = idx >> 4, c8 = idx & 15;
        int grow = row0 + r;
        uint4 v = make_uint4(0, 0, 0, 0);
        if (grow < nrows) {
            float4 a = ld4(X + (size_t)grow * 128 + c8 * 8);
            float4 b = ld4(X + (size_t)grow * 128 + c8 * 8 + 4);
            v = make_uint4(f2bf2(a.x, a.y), f2bf2(a.z, a.w), f2bf2(b.x, b.y), f2bf2(b.z, b.w));
        }
        *reinterpret_cast<uint4*>(&sX[r * LDR + c8 * 8]) = v;
    }
#pragma unroll
    for (int i = 0; i < 8; ++i) {
        int idx = tid + i * 256;
        int nn = idx >> 4, c8 = idx & 15;
        *reinterpret_cast<uint4*>(&sB[nn * LDR + c8 * 8]) =
            *reinterpret_cast<const uint4*>(Wt + (size_t)nn * 128 + c8 * 8);
    }
    __syncthreads();

    const int lane = tid & 63;
    const int wave = tid >> 6;
    const int l15  = lane & 15;
    const int quad = lane >> 4;

    floatx4 acc[8];
#pragma unroll
    for (int j = 0; j < 8; ++j) acc[j] = (floatx4){0.f, 0.f, 0.f, 0.f};

    const unsigned short* xbase = &sX[(wave * 16 + l15) * LDR + quad * 8];
#pragma unroll
    for (int kk = 0; kk < 4; ++kk) {
        short8 xb = *reinterpret_cast<const short8*>(xbase + kk * 32);
#pragma unroll
        for (int j = 0; j < 8; ++j) {
            short8 wa = *reinterpret_cast<const short8*>(&sB[(j * 16 + l15) * LDR + quad * 8 + kk * 32]);
            acc[j] = __builtin_amdgcn_mfma_f32_16x16x32_bf16(wa, xb, acc[j], 0, 0, 0);
        }
    }

    int xrow = row0 + wave * 16 + l15;
    if (xrow < nrows) {
#pragma unroll
        for (int j = 0; j < 8; ++j) {
            uint2 o = make_uint2(f2bf2(acc[j][0], acc[j][1]), f2bf2(acc[j][2], acc[j][3]));
            *reinterpret_cast<uint2*>(O + (size_t)xrow * 128 + j * 16 + quad * 4) = o;
        }
    }
}

// ---------------- scan kernels ----------------
__global__ __launch_bounds__(256) void k_scan_small(const int* __restrict__ bsum, int* __restrict__ boff, int nb) {
    __shared__ int s[256];
    int t = threadIdx.x;
    int v = (t < nb) ? bsum[t] : 0;
    s[t] = v;
    __syncthreads();
    for (int off = 1; off < 256; off <<= 1) {
        int x = (t >= off) ? s[t - off] : 0;
        __syncthreads();
        s[t] += x;
        __syncthreads();
    }
    if (t < nb) boff[t] = s[t] - v;  // exclusive
}

__global__ __launch_bounds__(256) void k_scan_final(const int* __restrict__ deg, const int* __restrict__ boff,
                                                    int* __restrict__ row_off, float* __restrict__ dinv, int n) {
    __shared__ int s[256];
    int t = threadIdx.x;
    int i = blockIdx.x * 256 + t;
    int v = (i < n) ? deg[i] : 0;
    s[t] = v;
    __syncthreads();
    for (int off = 1; off < 256; off <<= 1) {
        int x = (t >= off) ? s[t - off] : 0;
        __syncthreads();
        s[t] += x;
        __syncthreads();
    }
    int incl = s[t] + boff[blockIdx.x];
    if (i < n) {
        row_off[i] = incl - v;
        dinv[i]    = 1.0f / sqrtf((float)v + 1.0f);
        if (i == n - 1) row_off[n] = incl;
    }
}

__global__ __launch_bounds__(256) void k_fill(const int* __restrict__ src, const int* __restrict__ dst,
                                              const int* __restrict__ rank, const int* __restrict__ roff,
                                              const float* __restrict__ dinv, int2* __restrict__ cpair, int E) {
    int e = blockIdx.x * 256 + threadIdx.x;
    if (e < E) {
        int s = src[e], d = dst[e];
        int pos = roff[d] + rank[e];
        cpair[pos] = make_int2(s, __float_as_int(dinv[s] * dinv[d]));
    }
}

// ---------------- MFMA GEMM (layers 2/3): O[nrows x NC](bf16) = X(bf16)[nrows x 128] @ W ----------------
template <int NC>
__global__ __launch_bounds__(256) void k_gemm_mfma(const unsigned short* __restrict__ X,
                                                   const unsigned short* __restrict__ Wt,
                                                   unsigned short* __restrict__ O, int nrows) {
    constexpr int LDR = 136;
    __shared__ unsigned short sX[64 * LDR];
    __shared__ unsigned short sB[NC * LDR];

    const int tid  = threadIdx.x;
    const int row0 = blockIdx.x * 64;

#pragma unroll
    for (int i = 0; i < 4; ++i) {
        int idx = tid + i * 256;
        int r = idx >> 4, c8 = idx & 15;
        int grow = row0 + r;
        uint4 v = make_uint4(0, 0, 0, 0);
        if (grow < nrows) v = *reinterpret_cast<const uint4*>(X + (size_t)grow * 128 + c8 * 8);
        *reinterpret_cast<uint4*>(&sX[r * LDR + c8 * 8]) = v;
    }
#pragma unroll
    for (int i = 0; i < NC / 16; ++i) {
        int idx = tid + i * 256;
        int n = idx >> 4, c8 = idx & 15;
        *reinterpret_cast<uint4*>(&sB[n * LDR + c8 * 8]) =
            *reinterpret_cast<const uint4*>(Wt + (size_t)n * 128 + c8 * 8);
    }
    __syncthreads();

    const int lane = tid & 63;
    const int wave = tid >> 6;
    const int l15  = lane & 15;
    const int quad = lane >> 4;

    floatx4 acc[NC / 16];
#pragma unroll
    for (int j = 0; j < NC / 16; ++j) acc[j] = (floatx4){0.f, 0.f, 0.f, 0.f};

    const unsigned short* xbase = &sX[(wave * 16 + l15) * LDR + quad * 8];
#pragma unroll
    for (int kk = 0; kk < 4; ++kk) {
        short8 xb = *reinterpret_cast<const short8*>(xbase + kk * 32);
#pragma unroll
        for (int j = 0; j < NC / 16; ++j) {
            short8 wa = *reinterpret_cast<const short8*>(&sB[(j * 16 + l15) * LDR + quad * 8 + kk * 32]);
            acc[j] = __builtin_amdgcn_mfma_f32_16x16x32_bf16(wa, xb, acc[j], 0, 0, 0);
        }
    }

    int xrow = row0 + wave * 16 + l15;
    if (xrow < nrows) {
#pragma unroll
        for (int j = 0; j < NC / 16; ++j) {
            uint2 o = make_uint2(f2bf2(acc[j][0], acc[j][1]), f2bf2(acc[j][2], acc[j][3]));
            *reinterpret_cast<uint2*>(O + (size_t)xrow * NC + j * 16 + quad * 4) = o;
        }
    }
}

// ---------------- aggregation (128 feats, bf16 H) + bias + relu ----------------
// 16 lanes/node, 8 feats (16 B)/lane, 4-deep gather pipeline (R5 best-measured variant).
__global__ __launch_bounds__(256) void k_agg_relu(const unsigned short* __restrict__ H, const int* __restrict__ roff,
                                                  const int2* __restrict__ cpair, const float* __restrict__ dinv,
                                                  const float* __restrict__ bias, unsigned short* __restrict__ O, int n) {
    int t    = blockIdx.x * 256 + threadIdx.x;
    int node = t >> 4;
    int f8   = (t & 15) * 8;
    if (node >= n) return;

    float di = dinv[node];
    float sc = di * di;
    float a[8];
    {
        uint4 hv = *reinterpret_cast<const uint4*>(H + (size_t)node * 128 + f8);
        float h[8];
        unpack8(hv, h);
#pragma unroll
        for (int i = 0; i < 8; ++i) a[i] = h[i] * sc;
    }

    int e  = roff[node];
    int e1 = roff[node + 1];
    for (; e + 3 < e1; e += 4) {
        int2 p[4];
        uint4 v[4];
#pragma unroll
        for (int u = 0; u < 4; ++u) p[u] = cpair[e + u];
#pragma unroll
        for (int u = 0; u < 4; ++u) v[u] = *reinterpret_cast<const uint4*>(H + (size_t)p[u].x * 128 + f8);
#pragma unroll
        for (int u = 0; u < 4; ++u) {
            float nu = __int_as_float(p[u].y);
            float g[8];
            unpack8(v[u], g);
#pragma unroll
            for (int i = 0; i < 8; ++i) a[i] += g[i] * nu;
        }
    }
    for (; e < e1; ++e) {
        int2 p0 = cpair[e];
        float n0 = __int_as_float(p0.y);
        uint4 v0 = *reinterpret_cast<const uint4*>(H + (size_t)p0.x * 128 + f8);
        float g0[8];
        unpack8(v0, g0);
#pragma unroll
        for (int i = 0; i < 8; ++i) a[i] += g0[i] * n0;
    }

    float4 b0 = ld4(bias + f8);
    float4 b1 = ld4(bias + f8 + 4);
    float bb[8] = {b0.x, b0.y, b0.z, b0.w, b1.x, b1.y, b1.z, b1.w};
#pragma unroll
    for (int i = 0; i < 8; ++i) a[i] = fmaxf(a[i] + bb[i], 0.0f);

    uint4 ov = make_uint4(f2bf2(a[0], a[1]), f2bf2(a[2], a[3]), f2bf2(a[4], a[5]), f2bf2(a[6], a[7]));
    *reinterpret_cast<uint4*>(O + (size_t)node * 128 + f8) = ov;
}

// ---------------- aggregation (64 feats, bf16 H) + bias + log_softmax ----------------
// 8 lanes/node, 8 feats/lane, 8-deep gather pipeline (R5 variant).
__global__ __launch_bounds__(256) void k_agg_softmax(const unsigned short* __restrict__ H, const int* __restrict__ roff,
                                                     const int2* __restrict__ cpair, const float* __restrict__ dinv,
                                                     const float* __restrict__ bias, float* __restrict__ O, int n) {
    int t    = blockIdx.x * 256 + threadIdx.x;
    int node = t >> 3;
    int f8   = (t & 7) * 8;
    if (node >= n) return;

    float di = dinv[node];
    float sc = di * di;
    float a[8];
    {
        uint4 hv = *reinterpret_cast<const uint4*>(H + (size_t)node * 64 + f8);
        float h[8];
        unpack8(hv, h);
#pragma unroll
        for (int i = 0; i < 8; ++i) a[i] = h[i] * sc;
    }

    int e  = roff[node];
    int e1 = roff[node + 1];
    for (; e + 7 < e1; e += 8) {
        int2 pr[8];
        uint4 v[8];
#pragma unroll
        for (int u = 0; u < 8; ++u) pr[u] = cpair[e + u];
#pragma unroll
        for (int u = 0; u < 8; ++u) v[u] = *reinterpret_cast<const uint4*>(H + (size_t)pr[u].x * 64 + f8);
#pragma unroll
        for (int u = 0; u < 8; ++u) {
            float nu = __int_as_float(pr[u].y);
            float gg[8];
            unpack8(v[u], gg);
#pragma unroll
            for (int i = 0; i < 8; ++i) a[i] += gg[i] * nu;
        }
    }
    if (e + 3 < e1) {
        int2 pr[4];
        uint4 v[4];
#pragma unroll
        for (int u = 0; u < 4; ++u) pr[u] = cpair[e + u];
#pragma unroll
        for (int u = 0; u < 4; ++u) v[u] = *reinterpret_cast<const uint4*>(H + (size_t)pr[u].x * 64 + f8);
#pragma unroll
        for (int u = 0; u < 4; ++u) {
            float nu = __int_as_float(pr[u].y);
            float gg[8];
            unpack8(v[u], gg);
#pragma unroll
            for (int i = 0; i < 8; ++i) a[i] += gg[i] * nu;
        }
        e += 4;
    }
    for (; e < e1; ++e) {
        int2 p0 = cpair[e];
        float n0 = __int_as_float(p0.y);
        uint4 v0 = *reinterpret_cast<const uint4*>(H + (size_t)p0.x * 64 + f8);
        float g0[8];
        unpack8(v0, g0);
#pragma unroll
        for (int i = 0; i < 8; ++i) a[i] += g0[i] * n0;
    }

    float4 b0 = ld4(bias + f8);
    float4 b1 = ld4(bias + f8 + 4);
    float bb[8] = {b0.x, b0.y, b0.z, b0.w, b1.x, b1.y, b1.z, b1.w};
    float v[8];
#pragma unroll
    for (int i = 0; i < 8; ++i) v[i] = a[i] + bb[i];

    float m = v[0];
#pragma unroll
    for (int i = 1; i < 8; ++i) m = fmaxf(m, v[i]);
    m = fmaxf(m, __shfl_xor(m, 1));
    m = fmaxf(m, __shfl_xor(m, 2));
    m = fmaxf(m, __shfl_xor(m, 4));

    float ssum = 0.0f;
#pragma unroll
    for (int i = 0; i < 8; ++i) ssum += expf(v[i] - m);
    ssum += __shfl_xor(ssum, 1);
    ssum += __shfl_xor(ssum, 2);
    ssum += __shfl_xor(ssum, 4);
    float ls = logf(ssum);

    float* op = O + (size_t)node * 64 + f8;
    st4(op, make_float4(v[0] - m - ls, v[1] - m - ls, v[2] - m - ls, v[3] - m - ls));
    st4(op + 4, make_float4(v[4] - m - ls, v[5] - m - ls, v[6] - m - ls, v[7] - m - ls));
}

// ---------------- launch ----------------
extern "C" void kernel_launch(void* const* d_in, const int* in_sizes, int n_in,
                              void* d_out, int out_size, void* d_ws, size_t ws_size,
                              hipStream_t stream) {
    const float* x  = (const float*)d_in[0];
    const int*   ei = (const int*)d_in[1];
    const float* W1 = (const float*)d_in[2];
    const float* b1 = (const float*)d_in[3];
    const float* W2 = (const float*)d_in[4];
    const float* b2 = (const float*)d_in[5];
    const float* W3 = (const float*)d_in[6];
    const float* b3 = (const float*)d_in[7];
    float* out = (float*)d_out;

    const int N = in_sizes[0] / 128;
    const int E = in_sizes[1] / 2;
    const int* src = ei;
    const int* dst = ei + E;

    char* ws = (char*)d_ws;
    size_t off = 0;
    auto alloc = [&](size_t bytes) -> char* {
        char* p = ws + off;
        off = (off + bytes + 255) & ~(size_t)255;
        return p;
    };
    int nb  = (N + 255) / 256;
    int nbE = (E + 255) / 256;
    int blocks64 = (N + 63) / 64;

    int*   deg     = (int*)alloc((size_t)N * 4);
    int*   row_off = (int*)alloc(((size_t)N + 1) * 4);
    float* dinv    = (float*)alloc((size_t)N * 4);
    int*   bsum    = (int*)alloc((size_t)nb * 4);
    int*   boff    = (int*)alloc((size_t)nb * 4);
    int*   rank    = (int*)alloc((size_t)E * 4);
    int2*  cpair   = (int2*)alloc((size_t)E * 8);
    unsigned short* Wt1  = (unsigned short*)alloc(128 * 128 * 2);
    unsigned short* Wt2  = (unsigned short*)alloc(128 * 128 * 2);
    unsigned short* Wt3  = (unsigned short*)alloc(64 * 128 * 2);
    unsigned short* bufA = (unsigned short*)alloc((size_t)N * 128 * 2);
    unsigned short* bufB = (unsigned short*)alloc((size_t)N * 128 * 2);
    unsigned short* bufC = (unsigned short*)alloc((size_t)N * 64 * 2);
    (void)ws_size; (void)n_in; (void)out_size;

    hipMemsetAsync(deg, 0, (size_t)N * 4, stream);
    // A: edge count/rank + W transposes (independent)
    k_count_prep<<<nbE + 160, 256, 0, stream>>>(dst, deg, rank, E, nbE, W1, W2, W3, Wt1, Wt2, Wt3);
    // B: deg reduce + layer-1 GEMM (independent; both deps satisfied by A)
    k_reduce_gemm1<<<nb + blocks64, 256, 0, stream>>>(deg, bsum, N, nb, x, Wt1, bufA, N);
    k_scan_small<<<1, 256, 0, stream>>>(bsum, boff, nb);
    k_scan_final<<<nb, 256, 0, stream>>>(deg, boff, row_off, dinv, N);
    k_fill<<<nbE, 256, 0, stream>>>(src, dst, rank, row_off, dinv, cpair, E);

    // layer 1 aggregation
    k_agg_relu<<<((size_t)N * 16 + 255) / 256, 256, 0, stream>>>(bufA, row_off, cpair, dinv, b1, bufB, N);
    // layer 2
    k_gemm_mfma<128><<<blocks64, 256, 0, stream>>>(bufB, Wt2, bufA, N);
    k_agg_relu<<<((size_t)N * 16 + 255) / 256, 256, 0, stream>>>(bufA, row_off, cpair, dinv, b2, bufB, N);
    // layer 3 + log_softmax
    k_gemm_mfma<64><<<blocks64, 256, 0, stream>>>(bufB, Wt3, bufC, N);
    k_agg_softmax<<<((size_t)N * 8 + 255) / 256, 256, 0, stream>>>(bufC, row_off, cpair, dinv, b3, out, N);
}

// Round 9
// 252.265 us; speedup vs baseline: 1.0948x; 1.0160x over previous
//
#include <hip/hip_runtime.h>
#include <math.h>

// ---------------- helpers ----------------
typedef short short8 __attribute__((ext_vector_type(8)));
typedef float floatx4 __attribute__((ext_vector_type(4)));

__device__ __forceinline__ float4 ld4(const float* p) { return *reinterpret_cast<const float4*>(p); }
__device__ __forceinline__ void st4(float* p, float4 v) { *reinterpret_cast<float4*>(p) = v; }

__device__ __forceinline__ float bf2f(unsigned int u) { return __uint_as_float(u << 16); }
__device__ __forceinline__ unsigned int f2bf1(float f) {
    unsigned int x = __float_as_uint(f);
    return (x + 0x7fffu + ((x >> 16) & 1u)) >> 16;  // RNE
}
__device__ __forceinline__ unsigned int f2bf2(float lo, float hi) {
    return f2bf1(lo) | (f2bf1(hi) << 16);
}
__device__ __forceinline__ void unpack8(uint4 v, float* f) {
    f[0] = bf2f(v.x & 0xffffu); f[1] = bf2f(v.x >> 16);
    f[2] = bf2f(v.y & 0xffffu); f[3] = bf2f(v.y >> 16);
    f[4] = bf2f(v.z & 0xffffu); f[5] = bf2f(v.z >> 16);
    f[6] = bf2f(v.w & 0xffffu); f[7] = bf2f(v.w >> 16);
}

// ---------------- launch A: edge count/rank + all-W transpose ----------------
__global__ __launch_bounds__(256) void k_count_prep(const int* __restrict__ dst, int* __restrict__ deg,
                                                    int* __restrict__ rank, int E, int nbE,
                                                    const float* __restrict__ W1, const float* __restrict__ W2,
                                                    const float* __restrict__ W3, unsigned short* __restrict__ Wt1,
                                                    unsigned short* __restrict__ Wt2, unsigned short* __restrict__ Wt3) {
    if ((int)blockIdx.x < nbE) {
        int e = blockIdx.x * 256 + threadIdx.x;
        if (e < E) rank[e] = atomicAdd(&deg[dst[e]], 1);
    } else {
        int t = (blockIdx.x - nbE) * 256 + threadIdx.x;
        if (t < 16384) {
            int k = t & 127, n = t >> 7;
            Wt1[n * 128 + k] = (unsigned short)f2bf1(W1[(size_t)k * 128 + n]);
        } else if (t < 32768) {
            int u = t - 16384;
            int k = u & 127, n = u >> 7;
            Wt2[n * 128 + k] = (unsigned short)f2bf1(W2[(size_t)k * 128 + n]);
        } else if (t < 40960) {
            int u = t - 32768;
            int k = u & 127, n = u >> 7;
            Wt3[n * 128 + k] = (unsigned short)f2bf1(W3[(size_t)k * 64 + n]);
        }
    }
}

// ---------------- launch B: deg block-reduce + layer-1 MFMA GEMM (unscaled output) ----------------
__global__ __launch_bounds__(256) void k_reduce_gemm1(const int* __restrict__ deg, int* __restrict__ bsum, int n, int nb,
                                                      const float* __restrict__ X, const unsigned short* __restrict__ Wt,
                                                      unsigned short* __restrict__ O, int nrows) {
    constexpr int LDR = 136;
    __shared__ __align__(16) unsigned char smem[(64 * LDR + 128 * LDR) * 2];  // 52224 B

    const int tid = threadIdx.x;
    if ((int)blockIdx.x < nb) {
        int* s = (int*)smem;
        int i = blockIdx.x * 256 + tid;
        s[tid] = (i < n) ? deg[i] : 0;
        __syncthreads();
        for (int off = 128; off > 0; off >>= 1) {
            if (tid < off) s[tid] += s[tid + off];
            __syncthreads();
        }
        if (tid == 0) bsum[blockIdx.x] = s[0];
        return;
    }

    unsigned short* sX = (unsigned short*)smem;
    unsigned short* sB = sX + 64 * LDR;
    const int row0 = (blockIdx.x - nb) * 64;

#pragma unroll
    for (int i = 0; i < 4; ++i) {
        int idx = tid + i * 256;
        int r = idx >> 4, c8 = idx & 15;
        int grow = row0 + r;
        uint4 v = make_uint4(0, 0, 0, 0);
        if (grow < nrows) {
            float4 a = ld4(X + (size_t)grow * 128 + c8 * 8);
            float4 b = ld4(X + (size_t)grow * 128 + c8 * 8 + 4);
            v = make_uint4(f2bf2(a.x, a.y), f2bf2(a.z, a.w), f2bf2(b.x, b.y), f2bf2(b.z, b.w));
        }
        *reinterpret_cast<uint4*>(&sX[r * LDR + c8 * 8]) = v;
    }
#pragma unroll
    for (int i = 0; i < 8; ++i) {
        int idx = tid + i * 256;
        int nn = idx >> 4, c8 = idx & 15;
        *reinterpret_cast<uint4*>(&sB[nn * LDR + c8 * 8]) =
            *reinterpret_cast<const uint4*>(Wt + (size_t)nn * 128 + c8 * 8);
    }
    __syncthreads();

    const int lane = tid & 63;
    const int wave = tid >> 6;
    const int l15  = lane & 15;
    const int quad = lane >> 4;

    floatx4 acc[8];
#pragma unroll
    for (int j = 0; j < 8; ++j) acc[j] = (floatx4){0.f, 0.f, 0.f, 0.f};

    const unsigned short* xbase = &sX[(wave * 16 + l15) * LDR + quad * 8];
#pragma unroll
    for (int kk = 0; kk < 4; ++kk) {
        short8 xb = *reinterpret_cast<const short8*>(xbase + kk * 32);
#pragma unroll
        for (int j = 0; j < 8; ++j) {
            short8 wa = *reinterpret_cast<const short8*>(&sB[(j * 16 + l15) * LDR + quad * 8 + kk * 32]);
            acc[j] = __builtin_amdgcn_mfma_f32_16x16x32_bf16(wa, xb, acc[j], 0, 0, 0);
        }
    }

    int xrow = row0 + wave * 16 + l15;
    if (xrow < nrows) {
#pragma unroll
        for (int j = 0; j < 8; ++j) {
            uint2 o = make_uint2(f2bf2(acc[j][0], acc[j][1]), f2bf2(acc[j][2], acc[j][3]));
            *reinterpret_cast<uint2*>(O + (size_t)xrow * 128 + j * 16 + quad * 4) = o;
        }
    }
}

// ---------------- scan kernels ----------------
__global__ __launch_bounds__(256) void k_scan_small(const int* __restrict__ bsum, int* __restrict__ boff, int nb) {
    __shared__ int s[256];
    int t = threadIdx.x;
    int v = (t < nb) ? bsum[t] : 0;
    s[t] = v;
    __syncthreads();
    for (int off = 1; off < 256; off <<= 1) {
        int x = (t >= off) ? s[t - off] : 0;
        __syncthreads();
        s[t] += x;
        __syncthreads();
    }
    if (t < nb) boff[t] = s[t] - v;  // exclusive
}

__global__ __launch_bounds__(256) void k_scan_final(const int* __restrict__ deg, const int* __restrict__ boff,
                                                    int* __restrict__ row_off, float* __restrict__ dinv, int n) {
    __shared__ int s[256];
    int t = threadIdx.x;
    int i = blockIdx.x * 256 + t;
    int v = (i < n) ? deg[i] : 0;
    s[t] = v;
    __syncthreads();
    for (int off = 1; off < 256; off <<= 1) {
        int x = (t >= off) ? s[t - off] : 0;
        __syncthreads();
        s[t] += x;
        __syncthreads();
    }
    int incl = s[t] + boff[blockIdx.x];
    if (i < n) {
        row_off[i] = incl - v;
        dinv[i]    = 1.0f / sqrtf((float)v + 1.0f);
        if (i == n - 1) row_off[n] = incl;
    }
}

// ---------------- launch C: CSR fill (4B scatter) + bufA *= dinv[row] scale ----------------
// blocks [0, nbE): fill; blocks [nbE, nbE+nbS): scale bufA (N x 128 bf16, 8 elems/thread).
__global__ __launch_bounds__(256) void k_fill_scale(const int* __restrict__ src, const int* __restrict__ dst,
                                                    const int* __restrict__ rank, const int* __restrict__ roff,
                                                    int* __restrict__ csrc, int E, int nbE,
                                                    unsigned short* __restrict__ A, const float* __restrict__ dinv,
                                                    int n16) {
    if ((int)blockIdx.x < nbE) {
        int e = blockIdx.x * 256 + threadIdx.x;
        if (e < E) csrc[roff[dst[e]] + rank[e]] = src[e];
    } else {
        int idx = (blockIdx.x - nbE) * 256 + threadIdx.x;
        if (idx < n16) {
            float di = dinv[idx >> 4];
            uint4 v = *reinterpret_cast<const uint4*>(A + (size_t)idx * 8);
            float f[8];
            unpack8(v, f);
#pragma unroll
            for (int i = 0; i < 8; ++i) f[i] *= di;
            uint4 o = make_uint4(f2bf2(f[0], f[1]), f2bf2(f[2], f[3]), f2bf2(f[4], f[5]), f2bf2(f[6], f[7]));
            *reinterpret_cast<uint4*>(A + (size_t)idx * 8) = o;
        }
    }
}

// ---------------- MFMA GEMM (layers 2/3): O = (X @ W) * dinv[row], bf16 ----------------
template <int NC>
__global__ __launch_bounds__(256) void k_gemm_mfma(const unsigned short* __restrict__ X,
                                                   const unsigned short* __restrict__ Wt,
                                                   const float* __restrict__ dinv,
                                                   unsigned short* __restrict__ O, int nrows) {
    constexpr int LDR = 136;
    __shared__ unsigned short sX[64 * LDR];
    __shared__ unsigned short sB[NC * LDR];

    const int tid  = threadIdx.x;
    const int row0 = blockIdx.x * 64;

#pragma unroll
    for (int i = 0; i < 4; ++i) {
        int idx = tid + i * 256;
        int r = idx >> 4, c8 = idx & 15;
        int grow = row0 + r;
        uint4 v = make_uint4(0, 0, 0, 0);
        if (grow < nrows) v = *reinterpret_cast<const uint4*>(X + (size_t)grow * 128 + c8 * 8);
        *reinterpret_cast<uint4*>(&sX[r * LDR + c8 * 8]) = v;
    }
#pragma unroll
    for (int i = 0; i < NC / 16; ++i) {
        int idx = tid + i * 256;
        int n = idx >> 4, c8 = idx & 15;
        *reinterpret_cast<uint4*>(&sB[n * LDR + c8 * 8]) =
            *reinterpret_cast<const uint4*>(Wt + (size_t)n * 128 + c8 * 8);
    }
    __syncthreads();

    const int lane = tid & 63;
    const int wave = tid >> 6;
    const int l15  = lane & 15;
    const int quad = lane >> 4;

    floatx4 acc[NC / 16];
#pragma unroll
    for (int j = 0; j < NC / 16; ++j) acc[j] = (floatx4){0.f, 0.f, 0.f, 0.f};

    const unsigned short* xbase = &sX[(wave * 16 + l15) * LDR + quad * 8];
#pragma unroll
    for (int kk = 0; kk < 4; ++kk) {
        short8 xb = *reinterpret_cast<const short8*>(xbase + kk * 32);
#pragma unroll
        for (int j = 0; j < NC / 16; ++j) {
            short8 wa = *reinterpret_cast<const short8*>(&sB[(j * 16 + l15) * LDR + quad * 8 + kk * 32]);
            acc[j] = __builtin_amdgcn_mfma_f32_16x16x32_bf16(wa, xb, acc[j], 0, 0, 0);
        }
    }

    int xrow = row0 + wave * 16 + l15;
    if (xrow < nrows) {
        float di = dinv[xrow];
#pragma unroll
        for (int j = 0; j < NC / 16; ++j) {
            uint2 o = make_uint2(f2bf2(acc[j][0] * di, acc[j][1] * di), f2bf2(acc[j][2] * di, acc[j][3] * di));
            *reinterpret_cast<uint2*>(O + (size_t)xrow * NC + j * 16 + quad * 4) = o;
        }
    }
}

// ---------------- aggregation (128 feats, pre-scaled bf16 H') + bias + relu ----------------
// out = relu(dinv[node] * (sum H'[src] + H'[node]) + b). 16 lanes/node, 8 feats/lane, 4-deep.
__global__ __launch_bounds__(256) void k_agg_relu(const unsigned short* __restrict__ H, const int* __restrict__ roff,
                                                  const int* __restrict__ csrc, const float* __restrict__ dinv,
                                                  const float* __restrict__ bias, unsigned short* __restrict__ O, int n) {
    int t    = blockIdx.x * 256 + threadIdx.x;
    int node = t >> 4;
    int f8   = (t & 15) * 8;
    if (node >= n) return;

    float a[8];
    {
        uint4 hv = *reinterpret_cast<const uint4*>(H + (size_t)node * 128 + f8);
        unpack8(hv, a);  // self term H'[node]
    }

    int e  = roff[node];
    int e1 = roff[node + 1];
    for (; e + 3 < e1; e += 4) {
        int s[4];
        uint4 v[4];
#pragma unroll
        for (int u = 0; u < 4; ++u) s[u] = csrc[e + u];
#pragma unroll
        for (int u = 0; u < 4; ++u) v[u] = *reinterpret_cast<const uint4*>(H + (size_t)s[u] * 128 + f8);
#pragma unroll
        for (int u = 0; u < 4; ++u) {
            float g[8];
            unpack8(v[u], g);
#pragma unroll
            for (int i = 0; i < 8; ++i) a[i] += g[i];
        }
    }
    for (; e < e1; ++e) {
        uint4 v0 = *reinterpret_cast<const uint4*>(H + (size_t)csrc[e] * 128 + f8);
        float g0[8];
        unpack8(v0, g0);
#pragma unroll
        for (int i = 0; i < 8; ++i) a[i] += g0[i];
    }

    float di = dinv[node];
    float4 b0 = ld4(bias + f8);
    float4 b1 = ld4(bias + f8 + 4);
    float bb[8] = {b0.x, b0.y, b0.z, b0.w, b1.x, b1.y, b1.z, b1.w};
#pragma unroll
    for (int i = 0; i < 8; ++i) a[i] = fmaxf(a[i] * di + bb[i], 0.0f);

    uint4 ov = make_uint4(f2bf2(a[0], a[1]), f2bf2(a[2], a[3]), f2bf2(a[4], a[5]), f2bf2(a[6], a[7]));
    *reinterpret_cast<uint4*>(O + (size_t)node * 128 + f8) = ov;
}

// ---------------- aggregation (64 feats, pre-scaled bf16 H') + bias + log_softmax ----------------
// 8 lanes/node, 8 feats/lane, 8-deep.
__global__ __launch_bounds__(256) void k_agg_softmax(const unsigned short* __restrict__ H, const int* __restrict__ roff,
                                                     const int* __restrict__ csrc, const float* __restrict__ dinv,
                                                     const float* __restrict__ bias, float* __restrict__ O, int n) {
    int t    = blockIdx.x * 256 + threadIdx.x;
    int node = t >> 3;
    int f8   = (t & 7) * 8;
    if (node >= n) return;

    float a[8];
    {
        uint4 hv = *reinterpret_cast<const uint4*>(H + (size_t)node * 64 + f8);
        unpack8(hv, a);  // self term
    }

    int e  = roff[node];
    int e1 = roff[node + 1];
    for (; e + 7 < e1; e += 8) {
        int s[8];
        uint4 v[8];
#pragma unroll
        for (int u = 0; u < 8; ++u) s[u] = csrc[e + u];
#pragma unroll
        for (int u = 0; u < 8; ++u) v[u] = *reinterpret_cast<const uint4*>(H + (size_t)s[u] * 64 + f8);
#pragma unroll
        for (int u = 0; u < 8; ++u) {
            float gg[8];
            unpack8(v[u], gg);
#pragma unroll
            for (int i = 0; i < 8; ++i) a[i] += gg[i];
        }
    }
    if (e + 3 < e1) {
        int s[4];
        uint4 v[4];
#pragma unroll
        for (int u = 0; u < 4; ++u) s[u] = csrc[e + u];
#pragma unroll
        for (int u = 0; u < 4; ++u) v[u] = *reinterpret_cast<const uint4*>(H + (size_t)s[u] * 64 + f8);
#pragma unroll
        for (int u = 0; u < 4; ++u) {
            float gg[8];
            unpack8(v[u], gg);
#pragma unroll
            for (int i = 0; i < 8; ++i) a[i] += gg[i];
        }
        e += 4;
    }
    for (; e < e1; ++e) {
        uint4 v0 = *reinterpret_cast<const uint4*>(H + (size_t)csrc[e] * 64 + f8);
        float g0[8];
        unpack8(v0, g0);
#pragma unroll
        for (int i = 0; i < 8; ++i) a[i] += g0[i];
    }

    float di = dinv[node];
    float4 b0 = ld4(bias + f8);
    float4 b1 = ld4(bias + f8 + 4);
    float bb[8] = {b0.x, b0.y, b0.z, b0.w, b1.x, b1.y, b1.z, b1.w};
    float v[8];
#pragma unroll
    for (int i = 0; i < 8; ++i) v[i] = a[i] * di + bb[i];

    float m = v[0];
#pragma unroll
    for (int i = 1; i < 8; ++i) m = fmaxf(m, v[i]);
    m = fmaxf(m, __shfl_xor(m, 1));
    m = fmaxf(m, __shfl_xor(m, 2));
    m = fmaxf(m, __shfl_xor(m, 4));

    float ssum = 0.0f;
#pragma unroll
    for (int i = 0; i < 8; ++i) ssum += expf(v[i] - m);
    ssum += __shfl_xor(ssum, 1);
    ssum += __shfl_xor(ssum, 2);
    ssum += __shfl_xor(ssum, 4);
    float ls = logf(ssum);

    float* op = O + (size_t)node * 64 + f8;
    st4(op, make_float4(v[0] - m - ls, v[1] - m - ls, v[2] - m - ls, v[3] - m - ls));
    st4(op + 4, make_float4(v[4] - m - ls, v[5] - m - ls, v[6] - m - ls, v[7] - m - ls));
}

// ---------------- launch ----------------
extern "C" void kernel_launch(void* const* d_in, const int* in_sizes, int n_in,
                              void* d_out, int out_size, void* d_ws, size_t ws_size,
                              hipStream_t stream) {
    const float* x  = (const float*)d_in[0];
    const int*   ei = (const int*)d_in[1];
    const float* W1 = (const float*)d_in[2];
    const float* b1 = (const float*)d_in[3];
    const float* W2 = (const float*)d_in[4];
    const float* b2 = (const float*)d_in[5];
    const float* W3 = (const float*)d_in[6];
    const float* b3 = (const float*)d_in[7];
    float* out = (float*)d_out;

    const int N = in_sizes[0] / 128;
    const int E = in_sizes[1] / 2;
    const int* src = ei;
    const int* dst = ei + E;

    char* ws = (char*)d_ws;
    size_t off = 0;
    auto alloc = [&](size_t bytes) -> char* {
        char* p = ws + off;
        off = (off + bytes + 255) & ~(size_t)255;
        return p;
    };
    int nb  = (N + 255) / 256;
    int nbE = (E + 255) / 256;
    int blocks64 = (N + 63) / 64;
    int n16 = N * 16;                     // uint4 chunks in bufA
    int nbS = (n16 + 255) / 256;

    int*   deg     = (int*)alloc((size_t)N * 4);
    int*   row_off = (int*)alloc(((size_t)N + 1) * 4);
    float* dinv    = (float*)alloc((size_t)N * 4);
    int*   bsum    = (int*)alloc((size_t)nb * 4);
    int*   boff    = (int*)alloc((size_t)nb * 4);
    int*   rank    = (int*)alloc((size_t)E * 4);
    int*   csrc    = (int*)alloc((size_t)E * 4);
    unsigned short* Wt1  = (unsigned short*)alloc(128 * 128 * 2);
    unsigned short* Wt2  = (unsigned short*)alloc(128 * 128 * 2);
    unsigned short* Wt3  = (unsigned short*)alloc(64 * 128 * 2);
    unsigned short* bufA = (unsigned short*)alloc((size_t)N * 128 * 2);
    unsigned short* bufB = (unsigned short*)alloc((size_t)N * 128 * 2);
    unsigned short* bufC = (unsigned short*)alloc((size_t)N * 64 * 2);
    (void)ws_size; (void)n_in; (void)out_size;

    hipMemsetAsync(deg, 0, (size_t)N * 4, stream);
    // A: edge count/rank + W transposes (independent)
    k_count_prep<<<nbE + 160, 256, 0, stream>>>(dst, deg, rank, E, nbE, W1, W2, W3, Wt1, Wt2, Wt3);
    // B: deg reduce + layer-1 GEMM (unscaled)
    k_reduce_gemm1<<<nb + blocks64, 256, 0, stream>>>(deg, bsum, N, nb, x, Wt1, bufA, N);
    k_scan_small<<<1, 256, 0, stream>>>(bsum, boff, nb);
    k_scan_final<<<nb, 256, 0, stream>>>(deg, boff, row_off, dinv, N);
    // C: CSR fill (4B) + bufA *= dinv
    k_fill_scale<<<nbE + nbS, 256, 0, stream>>>(src, dst, rank, row_off, csrc, E, nbE, bufA, dinv, n16);

    // layer 1 aggregation (pre-scaled bufA)
    k_agg_relu<<<((size_t)N * 16 + 255) / 256, 256, 0, stream>>>(bufA, row_off, csrc, dinv, b1, bufB, N);
    // layer 2 (epilogue scales by dinv)
    k_gemm_mfma<128><<<blocks64, 256, 0, stream>>>(bufB, Wt2, dinv, bufA, N);
    k_agg_relu<<<((size_t)N * 16 + 255) / 256, 256, 0, stream>>>(bufA, row_off, csrc, dinv, b2, bufB, N);
    // layer 3 + log_softmax
    k_gemm_mfma<64><<<blocks64, 256, 0, stream>>>(bufB, Wt3, dinv, bufC, N);
    k_agg_softmax<<<((size_t)N * 8 + 255) / 256, 256, 0, stream>>>(bufC, row_off, csrc, dinv, b3, out, N);
}